// Round 10
// baseline (381.388 us; speedup 1.0000x reference)
//
#include <hip/hip_runtime.h>

#define NEGV -10000000000.0f

typedef _Float16 half8 __attribute__((ext_vector_type(8)));
typedef float f32x4 __attribute__((ext_vector_type(4)));

__device__ __forceinline__ void gld16(const void* g, void* l) {
  __builtin_amdgcn_global_load_lds((const __attribute__((address_space(1))) void*)g,
                                   (__attribute__((address_space(3))) void*)l,
                                   16, 0, 0);
}

__device__ __forceinline__ float fast_tanh(float x) {
  const float e = __expf(2.0f * x);
  return 1.0f - 2.0f * __builtin_amdgcn_rcpf(e + 1.0f);
}

// ---------------------------------------------------------------------------
// PREP (one launch): blocks [0,128) hproj | [128,1152) wconv.
// (encconv is fused into the GEMM as a block-local pre-pass.)
// ---------------------------------------------------------------------------
__global__ __launch_bounds__(256) void prep_kernel(
    const float* __restrict__ We, _Float16* __restrict__ W16T,
    const float* __restrict__ hidden, const float* __restrict__ W_h,
    const float* __restrict__ b_h, const float* __restrict__ b_e,
    float* __restrict__ hpb) {
  __shared__ float tile[32][33];
  const int bid = blockIdx.x;
  const int tid = threadIdx.x;

  if (bid < 128) {
    // ---- hproj ----
    const int b = bid >> 2;
    const int h = ((bid & 3) << 8) | tid;
    const float* hb = hidden + b * 1024;
    float a0 = 0.f, a1 = 0.f, a2 = 0.f, a3 = 0.f;
    #pragma unroll 4
    for (int k = 0; k < 1024; k += 4) {
      a0 = fmaf(hb[k + 0], W_h[(size_t)(k + 0) * 1024 + h], a0);
      a1 = fmaf(hb[k + 1], W_h[(size_t)(k + 1) * 1024 + h], a1);
      a2 = fmaf(hb[k + 2], W_h[(size_t)(k + 2) * 1024 + h], a2);
      a3 = fmaf(hb[k + 3], W_h[(size_t)(k + 3) * 1024 + h], a3);
    }
    hpb[b * 1024 + h] = b_h[h] + b_e[h] + ((a0 + a1) + (a2 + a3));
  } else {
    // ---- wconv: W16T[n][k] = (fp16) W_e[k][n] ----
    const int tb = bid - 128;
    const int n0 = (tb & 31) << 5, k0 = (tb >> 5) << 5;
    const int tx = tid & 31, ty = tid >> 5;  // 32 x 8
    #pragma unroll
    for (int i = 0; i < 4; ++i) {
      const int r = ty + (i << 3);
      tile[r][tx] = We[(size_t)(k0 + r) * 1024 + n0 + tx];
    }
    __syncthreads();
    #pragma unroll
    for (int i = 0; i < 4; ++i) {
      const int r = ty + (i << 3);
      W16T[(size_t)(n0 + r) * 1024 + k0 + tx] = (_Float16)tile[tx][r];
    }
  }
}

// ---------------------------------------------------------------------------
// FUSED GEMM = block-local fp32->fp16 PRE-PASS + verbatim R6 K-loop.
//   logits[b,s] = mask ? v . tanh(hpb[b,:] + enc[b,s,:]@W_e) : NEG
// Pre-pass: each block converts its own 256 rows of enc (1MB->512KB) with
// plain vectorized loads/stores, then vmcnt(0)+threadfence+syncthreads once.
// K-loop (measured best, 165.6us/833TF): BM=256, BN=256 (4 panels), BK=32,
// 512 threads, 8 waves 2Mx4N, per-wave 128x64 (acc[8][4]); triple-buffered
// 16KB A/B tiles; stage t+2; per phase {ds_read; stage; barrier; lgkmcnt(0);
// setprio; 16 MFMA; barrier}; ONE vmcnt(4) per K-tile (never drains).
// Swizzle: g ^= (row>>1)&3 both sides (verified 0-conflict R4-R6).
// ---------------------------------------------------------------------------
__global__ __launch_bounds__(512, 2) void attn_gemm8_kernel(
    const float* __restrict__ enc32, _Float16* __restrict__ enc16,
    const _Float16* __restrict__ W16T,
    const float* __restrict__ hpb, const float* __restrict__ v,
    const int* __restrict__ mask, float* __restrict__ logits) {
  __shared__ __align__(16) _Float16 Abuf[3][256 * 32];  // 48 KB
  __shared__ __align__(16) _Float16 Bbuf[3][256 * 32];  // 48 KB
  __shared__ float hp_s[1024];
  __shared__ float vh_s[1024];
  __shared__ float red[1024];

  const int tid = threadIdx.x;
  const int wid = tid >> 6;
  const int lane = tid & 63;
  const int l15 = lane & 15;
  const int qq = lane >> 4;        // 16B granule within the 64B row
  const int wr = wid >> 2;         // 0..1: rows [wr*128, +128)
  const int wc = wid & 3;          // 0..3: cols [wc*64, +64) within the panel
  const int m0 = blockIdx.x << 8;  // 256 rows per block
  const int b = blockIdx.x >> 3;   // 8 blocks per batch

  // ================= PRE-PASS: convert own 256 rows fp32 -> fp16 ==========
  {
    const float* src = enc32 + (size_t)m0 * 1024;
    _Float16* dst = enc16 + (size_t)m0 * 1024;
    #pragma unroll 2
    for (int i = 0; i < 64; ++i) {
      const int idx = ((i << 9) + tid) << 3;  // 8 elems/thread/iter
      const float4 x = *(const float4*)(src + idx);
      const float4 y = *(const float4*)(src + idx + 4);
      half8 h;
      h[0] = (_Float16)x.x; h[1] = (_Float16)x.y; h[2] = (_Float16)x.z; h[3] = (_Float16)x.w;
      h[4] = (_Float16)y.x; h[5] = (_Float16)y.y; h[6] = (_Float16)y.z; h[7] = (_Float16)y.w;
      *(half8*)(dst + idx) = h;
    }
    asm volatile("s_waitcnt vmcnt(0)" ::: "memory");
    __threadfence();
    __syncthreads();
  }

  for (int i = tid; i < 1024; i += 512) {
    hp_s[i] = hpb[(b << 10) + i];
    vh_s[i] = v[i];
  }

  // ---- staging constants ----
  const int r0 = tid >> 2;                     // row for issue 0 (0..127)
  const int r1 = r0 + 128;                     // row for issue 1 (same swz bits)
  const int g0 = tid & 3;                      // 16B granule within 64B row
  const int sc = (g0 ^ ((r0 >> 1) & 3)) << 4;  // inverse-swizzled source col
  const int ldsoff0 = (wid << 10);
  const int ldsoff1 = (wid << 10) + 8192;

  const char* encb = (const char*)(enc16 + (size_t)m0 * 1024);
  const char* wb0 = (const char*)W16T;

  auto stageA = [&](int buf, int t) {
    const int colb = ((t & 31) << 6) + sc;  // BK=32 -> 64B k-tile per row
    char* base = (char*)(&Abuf[buf][0]);
    gld16(encb + (size_t)r0 * 2048 + colb, base + ldsoff0);
    gld16(encb + (size_t)r1 * 2048 + colb, base + ldsoff1);
  };
  auto stageB = [&](int buf, int t) {
    const char* wb = wb0 + ((size_t)(t >> 5) << 19);  // panel * 256*2048 B
    const int colb = ((t & 31) << 6) + sc;
    char* base = (char*)(&Bbuf[buf][0]);
    gld16(wb + (size_t)r0 * 2048 + colb, base + ldsoff0);
    gld16(wb + (size_t)r1 * 2048 + colb, base + ldsoff1);
  };

  // ---- read-side offsets (loop-invariant, swizzled) ----
  int aoff[2][4], boff[4];
  #pragma unroll
  for (int mh = 0; mh < 2; ++mh)
    #pragma unroll
    for (int mi = 0; mi < 4; ++mi) {
      const int row = (wr << 7) + (mh << 6) + (mi << 4) + l15;
      aoff[mh][mi] = (row << 6) + ((qq ^ ((row >> 1) & 3)) << 4);
    }
  #pragma unroll
  for (int ni = 0; ni < 4; ++ni) {
    const int np = (wc << 6) + (ni << 4) + l15;
    boff[ni] = (np << 6) + ((qq ^ ((np >> 1) & 3)) << 4);
  }

  f32x4 acc[8][4];
  float rowsum[8][4];
  #pragma unroll
  for (int mi = 0; mi < 8; ++mi)
    #pragma unroll
    for (int j = 0; j < 4; ++j) {
      acc[mi][j] = (f32x4){0.f, 0.f, 0.f, 0.f};
      rowsum[mi][j] = 0.f;
    }

  // ---- prologue: stage tiles 0,1 into buffers 0,1; full drain once ----
  stageA(0, 0); stageB(0, 0);
  stageA(1, 1); stageB(1, 1);
  __syncthreads();

  int bi = 0;
  #pragma unroll 1
  for (int t = 0; t < 128; ++t) {
    const int bi2 = (bi >= 1) ? bi - 1 : bi + 2;  // (bi+2)%3
    const char* A = (const char*)(&Abuf[bi][0]);
    const char* B = (const char*)(&Bbuf[bi][0]);
    half8 a[4], bf[4];

    // ======== phase 0: mh0 (stage A(t+2)) ========
    #pragma unroll
    for (int mi = 0; mi < 4; ++mi) a[mi] = *(const half8*)(A + aoff[0][mi]);
    #pragma unroll
    for (int ni = 0; ni < 4; ++ni) bf[ni] = *(const half8*)(B + boff[ni]);
    if (t < 126) stageA(bi2, t + 2);
    __builtin_amdgcn_s_barrier();
    asm volatile("s_waitcnt lgkmcnt(0)" ::: "memory");
    __builtin_amdgcn_s_setprio(1);
    #pragma unroll
    for (int mi = 0; mi < 4; ++mi)
      #pragma unroll
      for (int ni = 0; ni < 4; ++ni)
        acc[mi][ni] = __builtin_amdgcn_mfma_f32_16x16x32_f16(a[mi], bf[ni], acc[mi][ni], 0, 0, 0);
    __builtin_amdgcn_s_setprio(0);
    __builtin_amdgcn_s_barrier();

    // ======== phase 1: mh1 (reuse bf; stage B(t+2)) ========
    #pragma unroll
    for (int mi = 0; mi < 4; ++mi) a[mi] = *(const half8*)(A + aoff[1][mi]);
    if (t < 126) stageB(bi2, t + 2);
    __builtin_amdgcn_s_barrier();
    asm volatile("s_waitcnt lgkmcnt(0)" ::: "memory");
    __builtin_amdgcn_s_setprio(1);
    #pragma unroll
    for (int mi = 0; mi < 4; ++mi)
      #pragma unroll
      for (int ni = 0; ni < 4; ++ni)
        acc[4 + mi][ni] = __builtin_amdgcn_mfma_f32_16x16x32_f16(a[mi], bf[ni], acc[4 + mi][ni], 0, 0, 0);
    __builtin_amdgcn_s_setprio(0);

    // ---- tile end: counted wait (t+1 landed; t+2's 4 stay in flight) ----
    if (t < 126) asm volatile("s_waitcnt vmcnt(4)" ::: "memory");
    else         asm volatile("s_waitcnt vmcnt(0)" ::: "memory");
    __builtin_amdgcn_s_barrier();

    // ---- per-panel epilogue: rowsum += tanh(acc + hproj) * v ----
    if ((t & 31) == 31) {
      const int nt = t >> 5;
      const int hb = (nt << 8) + (wc << 6);
      #pragma unroll
      for (int ni = 0; ni < 4; ++ni) {
        const int h = hb + (ni << 4) + l15;
        const float hv = hp_s[h];
        const float vv = vh_s[h];
        #pragma unroll
        for (int mi = 0; mi < 8; ++mi) {
          #pragma unroll
          for (int r = 0; r < 4; ++r)
            rowsum[mi][r] += fast_tanh(acc[mi][ni][r] + hv) * vv;
          acc[mi][ni] = (f32x4){0.f, 0.f, 0.f, 0.f};
        }
      }
    }
    bi = (bi >= 2) ? 0 : bi + 1;
  }

  // ---- reduce across the 16 column-lanes of each wave ----
  #pragma unroll
  for (int mi = 0; mi < 8; ++mi)
    #pragma unroll
    for (int r = 0; r < 4; ++r) {
      float s = rowsum[mi][r];
      s += __shfl_xor(s, 1);
      s += __shfl_xor(s, 2);
      s += __shfl_xor(s, 4);
      s += __shfl_xor(s, 8);
      rowsum[mi][r] = s;
    }
  __syncthreads();
  if (l15 == 0) {
    #pragma unroll
    for (int mi = 0; mi < 8; ++mi)
      #pragma unroll
      for (int r = 0; r < 4; ++r) {
        const int row = (wr << 7) + (mi << 4) + (qq << 2) + r;
        red[(row << 2) + wc] = rowsum[mi][r];
      }
  }
  __syncthreads();
  if (tid < 256) {
    const float s = red[tid << 2] + red[(tid << 2) + 1] + red[(tid << 2) + 2] + red[(tid << 2) + 3];
    const int m = m0 + tid;
    logits[m] = (mask[(b << 11) + (m & 2047)] == 0) ? NEGV : s;
  }
}

// ---------------------------------------------------------------------------
// softmax over S=2048 per batch row -> attention weights (output 1)
// ---------------------------------------------------------------------------
__global__ void softmax_kernel(const float* __restrict__ logits, float* __restrict__ wout) {
  __shared__ float red[4];
  const int b = blockIdx.x, tid = threadIdx.x;
  const int wid = tid >> 6, lane = tid & 63;
  const float* lb = logits + b * 2048;
  float x[8];
  #pragma unroll
  for (int j = 0; j < 8; ++j) x[j] = lb[tid + j * 256];
  float m = x[0];
  #pragma unroll
  for (int j = 1; j < 8; ++j) m = fmaxf(m, x[j]);
  #pragma unroll
  for (int off = 32; off > 0; off >>= 1) m = fmaxf(m, __shfl_xor(m, off));
  if (lane == 0) red[wid] = m;
  __syncthreads();
  m = fmaxf(fmaxf(red[0], red[1]), fmaxf(red[2], red[3]));
  __syncthreads();
  float e[8];
  float s = 0.f;
  #pragma unroll
  for (int j = 0; j < 8; ++j) { e[j] = expf(x[j] - m); s += e[j]; }
  #pragma unroll
  for (int off = 32; off > 0; off >>= 1) s += __shfl_xor(s, off);
  if (lane == 0) red[wid] = s;
  __syncthreads();
  s = red[0] + red[1] + red[2] + red[3];
  const float inv = 1.0f / s;
  #pragma unroll
  for (int j = 0; j < 8; ++j) wout[b * 2048 + tid + j * 256] = e[j] * inv;
}

// ---------------------------------------------------------------------------
// context from fp16 enc: ctx[b,e] = sum_s w[b,s] * enc16[b,s,e]
// ---------------------------------------------------------------------------
__global__ void context16_kernel(const _Float16* __restrict__ enc16,
                                 const float* __restrict__ wout, float* __restrict__ ctx) {
  const int b = blockIdx.x >> 4;
  const int ch = blockIdx.x & 15;
  const int tl = threadIdx.x & 127;  // e-granule: 8 cols
  const int sh = threadIdx.x >> 7;   // 0/1: s interleave
  float a[8] = {0.f, 0.f, 0.f, 0.f, 0.f, 0.f, 0.f, 0.f};
  #pragma unroll 1
  for (int i = 0; i < 64; ++i) {
    const int s = (ch << 7) + (i << 1) + sh;
    const float w = wout[(b << 11) + s];
    const half8 r = *(const half8*)(enc16 + (((size_t)(b << 11) + s) << 10) + (tl << 3));
    #pragma unroll
    for (int j = 0; j < 8; ++j) a[j] = fmaf(w, (float)r[j], a[j]);
  }
  float* c = ctx + (b << 10) + (tl << 3);
  #pragma unroll
  for (int j = 0; j < 8; ++j) atomicAdd(c + j, a[j]);
}

// ---------------------------------------------------------------------------
extern "C" void kernel_launch(void* const* d_in, const int* in_sizes, int n_in,
                              void* d_out, int out_size, void* d_ws, size_t ws_size,
                              hipStream_t stream) {
  const float* hidden = (const float*)d_in[0];
  const float* enc    = (const float*)d_in[1];
  const int*   mask   = (const int*)d_in[2];
  const float* W_h    = (const float*)d_in[3];
  const float* b_h    = (const float*)d_in[4];
  const float* W_e    = (const float*)d_in[5];
  const float* b_e    = (const float*)d_in[6];
  const float* v      = (const float*)d_in[7];

  float* ctx  = (float*)d_out;              // context: 32*1024 floats
  float* wout = (float*)d_out + 32 * 1024;  // attention weights: 32*2048 floats

  char* ws = (char*)d_ws;
  const size_t ENC16_BYTES = 134217728ULL;  // 32*2048*1024 fp16
  _Float16* enc16 = (_Float16*)ws;
  _Float16* W16T  = (_Float16*)(ws + ENC16_BYTES);
  float* hpb      = (float*)(ws + ENC16_BYTES + 2097152);
  float* logits   = (float*)(ws + ENC16_BYTES + 2097152 + 131072);

  hipMemsetAsync(ctx, 0, 32 * 1024 * sizeof(float), stream);
  hipLaunchKernelGGL(prep_kernel, dim3(1152), dim3(256), 0, stream,
                     W_e, W16T, hidden, W_h, b_h, b_e, hpb);
  hipLaunchKernelGGL(attn_gemm8_kernel, dim3(256), dim3(512), 0, stream,
                     enc, enc16, W16T, hpb, v, mask, logits);
  hipLaunchKernelGGL(softmax_kernel, dim3(32), dim3(256), 0, stream, logits, wout);
  hipLaunchKernelGGL(context16_kernel, dim3(512), dim3(256), 0, stream, enc16, wout, ctx);
}

// Round 11
// 283.472 us; speedup vs baseline: 1.3454x; 1.3454x over previous
//
#include <hip/hip_runtime.h>

#define NEGV -10000000000.0f

typedef _Float16 half8 __attribute__((ext_vector_type(8)));
typedef float f32x4 __attribute__((ext_vector_type(4)));

__device__ __forceinline__ void gld16(const void* g, void* l) {
  __builtin_amdgcn_global_load_lds((const __attribute__((address_space(1))) void*)g,
                                   (__attribute__((address_space(3))) void*)l,
                                   16, 0, 0);
}

__device__ __forceinline__ float fast_tanh(float x) {
  const float e = __expf(2.0f * x);
  return 1.0f - 2.0f * __builtin_amdgcn_rcpf(e + 1.0f);
}

// ---------------------------------------------------------------------------
// PREP (one launch): blocks [0,128) hproj | [128,1152) wconv | rest encconv.
// (R6 configuration -- conversion fusion into the GEMM is abandoned: both
//  attempts regressed; standalone encconv is at its BW floor.)
// ---------------------------------------------------------------------------
__global__ __launch_bounds__(256) void prep_kernel(
    const float* __restrict__ enc, _Float16* __restrict__ enc16,
    const float* __restrict__ We, _Float16* __restrict__ W16T,
    const float* __restrict__ hidden, const float* __restrict__ W_h,
    const float* __restrict__ b_h, const float* __restrict__ b_e,
    float* __restrict__ hpb) {
  __shared__ float tile[32][33];
  const int bid = blockIdx.x;
  const int tid = threadIdx.x;

  if (bid < 128) {
    // ---- hproj ----
    const int b = bid >> 2;
    const int h = ((bid & 3) << 8) | tid;
    const float* hb = hidden + b * 1024;
    float a0 = 0.f, a1 = 0.f, a2 = 0.f, a3 = 0.f;
    #pragma unroll 4
    for (int k = 0; k < 1024; k += 4) {
      a0 = fmaf(hb[k + 0], W_h[(size_t)(k + 0) * 1024 + h], a0);
      a1 = fmaf(hb[k + 1], W_h[(size_t)(k + 1) * 1024 + h], a1);
      a2 = fmaf(hb[k + 2], W_h[(size_t)(k + 2) * 1024 + h], a2);
      a3 = fmaf(hb[k + 3], W_h[(size_t)(k + 3) * 1024 + h], a3);
    }
    hpb[b * 1024 + h] = b_h[h] + b_e[h] + ((a0 + a1) + (a2 + a3));
  } else if (bid < 128 + 1024) {
    // ---- wconv: W16T[n][k] = (fp16) W_e[k][n] ----
    const int tb = bid - 128;
    const int n0 = (tb & 31) << 5, k0 = (tb >> 5) << 5;
    const int tx = tid & 31, ty = tid >> 5;  // 32 x 8
    #pragma unroll
    for (int i = 0; i < 4; ++i) {
      const int r = ty + (i << 3);
      tile[r][tx] = We[(size_t)(k0 + r) * 1024 + n0 + tx];
    }
    __syncthreads();
    #pragma unroll
    for (int i = 0; i < 4; ++i) {
      const int r = ty + (i << 3);
      W16T[(size_t)(n0 + r) * 1024 + k0 + tx] = (_Float16)tile[tx][r];
    }
  } else {
    // ---- encconv: fp32 -> fp16 ----
    const size_t base = ((size_t)(bid - 1152) * 256 + tid) * 8;
    const float4 x = *(const float4*)(enc + base);
    const float4 y = *(const float4*)(enc + base + 4);
    half8 h;
    h[0] = (_Float16)x.x; h[1] = (_Float16)x.y; h[2] = (_Float16)x.z; h[3] = (_Float16)x.w;
    h[4] = (_Float16)y.x; h[5] = (_Float16)y.y; h[6] = (_Float16)y.z; h[7] = (_Float16)y.w;
    *(half8*)(enc16 + base) = h;
  }
}

// ---------------------------------------------------------------------------
// FUSED GEMM = R6 data path, SINGLE barrier per K-tile:
//   logits[b,s] = mask ? v . tanh(hpb[b,:] + enc[b,s,:]@W_e) : NEG
// BM=256, BN=256 (4 panels), BK=32, 512 threads, 8 waves 2Mx4N, per-wave
// 128x64 (acc[8][4]). Triple-buffered 16KB A/B tiles; stage t+2.
// Per tile: issue ALL 12 ds_reads, then 4 gld_lds stages, then both MFMA
// clusters -- NO mid-tile barriers, NO blanket lgkmcnt(0): the compiler's
// per-operand lgkm waits let MFMAs start while later reads drain (the R6
// structure alternated reads and MFMA on the critical path = the 36% util
// ceiling). Sync per tile: vmcnt(4) ("memory" asm = motion fence) then
// s_barrier. Safety: reads of buf t%3 all precede the barrier by data-dep
// (mh1 MFMAs consume read #12); each wave's vmcnt(4) retires its OWN t+1
// stage-writes before the barrier publishes them (cross-wave staging dep);
// buffer t%3 is only rewritten by stages issued AFTER that barrier (t+1 ->
// buf (t+3)%3 = t%3). Ledger unchanged from R6 (2-tile leash, never drains).
// Swizzle: g ^= (row>>1)&3 both sides (verified 0-conflict R4-R6).
// ---------------------------------------------------------------------------
__global__ __launch_bounds__(512, 2) void attn_gemm8_kernel(
    const _Float16* __restrict__ enc16, const _Float16* __restrict__ W16T,
    const float* __restrict__ hpb, const float* __restrict__ v,
    const int* __restrict__ mask, float* __restrict__ logits) {
  __shared__ __align__(16) _Float16 Abuf[3][256 * 32];  // 48 KB
  __shared__ __align__(16) _Float16 Bbuf[3][256 * 32];  // 48 KB
  __shared__ float hp_s[1024];
  __shared__ float vh_s[1024];
  __shared__ float red[1024];

  const int tid = threadIdx.x;
  const int wid = tid >> 6;
  const int lane = tid & 63;
  const int l15 = lane & 15;
  const int qq = lane >> 4;        // 16B granule within the 64B row
  const int wr = wid >> 2;         // 0..1: rows [wr*128, +128)
  const int wc = wid & 3;          // 0..3: cols [wc*64, +64) within the panel
  const int m0 = blockIdx.x << 8;  // 256 rows per block
  const int b = blockIdx.x >> 3;   // 8 blocks per batch

  for (int i = tid; i < 1024; i += 512) {
    hp_s[i] = hpb[(b << 10) + i];
    vh_s[i] = v[i];
  }

  // ---- staging constants ----
  const int r0 = tid >> 2;                     // row for issue 0 (0..127)
  const int r1 = r0 + 128;                     // row for issue 1 (same swz bits)
  const int g0 = tid & 3;                      // 16B granule within 64B row
  const int sc = (g0 ^ ((r0 >> 1) & 3)) << 4;  // inverse-swizzled source col
  const int ldsoff0 = (wid << 10);
  const int ldsoff1 = (wid << 10) + 8192;

  const char* encb = (const char*)(enc16 + (size_t)m0 * 1024);
  const char* wb0 = (const char*)W16T;

  auto stageA = [&](int buf, int t) {
    const int colb = ((t & 31) << 6) + sc;  // BK=32 -> 64B k-tile per row
    char* base = (char*)(&Abuf[buf][0]);
    gld16(encb + (size_t)r0 * 2048 + colb, base + ldsoff0);
    gld16(encb + (size_t)r1 * 2048 + colb, base + ldsoff1);
  };
  auto stageB = [&](int buf, int t) {
    const char* wb = wb0 + ((size_t)(t >> 5) << 19);  // panel * 256*2048 B
    const int colb = ((t & 31) << 6) + sc;
    char* base = (char*)(&Bbuf[buf][0]);
    gld16(wb + (size_t)r0 * 2048 + colb, base + ldsoff0);
    gld16(wb + (size_t)r1 * 2048 + colb, base + ldsoff1);
  };

  // ---- read-side offsets (loop-invariant, swizzled) ----
  int aoff[2][4], boff[4];
  #pragma unroll
  for (int mh = 0; mh < 2; ++mh)
    #pragma unroll
    for (int mi = 0; mi < 4; ++mi) {
      const int row = (wr << 7) + (mh << 6) + (mi << 4) + l15;
      aoff[mh][mi] = (row << 6) + ((qq ^ ((row >> 1) & 3)) << 4);
    }
  #pragma unroll
  for (int ni = 0; ni < 4; ++ni) {
    const int np = (wc << 6) + (ni << 4) + l15;
    boff[ni] = (np << 6) + ((qq ^ ((np >> 1) & 3)) << 4);
  }

  f32x4 acc[8][4];
  float rowsum[8][4];
  #pragma unroll
  for (int mi = 0; mi < 8; ++mi)
    #pragma unroll
    for (int j = 0; j < 4; ++j) {
      acc[mi][j] = (f32x4){0.f, 0.f, 0.f, 0.f};
      rowsum[mi][j] = 0.f;
    }

  // ---- prologue: stage tiles 0,1; __syncthreads drains vm+lgkm fully ----
  stageA(0, 0); stageB(0, 0);
  stageA(1, 1); stageB(1, 1);
  __syncthreads();

  int bi = 0;
  #pragma unroll 1
  for (int t = 0; t < 128; ++t) {
    const int bi2 = (bi >= 1) ? bi - 1 : bi + 2;  // (bi+2)%3
    const char* A = (const char*)(&Abuf[bi][0]);
    const char* B = (const char*)(&Bbuf[bi][0]);
    half8 a0[4], a1[4], bf[4];

    // ---- issue all 12 ds_reads up front (compiler places counted waits) ----
    #pragma unroll
    for (int mi = 0; mi < 4; ++mi) a0[mi] = *(const half8*)(A + aoff[0][mi]);
    #pragma unroll
    for (int ni = 0; ni < 4; ++ni) bf[ni] = *(const half8*)(B + boff[ni]);
    #pragma unroll
    for (int mi = 0; mi < 4; ++mi) a1[mi] = *(const half8*)(A + aoff[1][mi]);

    // ---- stage tile t+2 (writes buf bi2; no overlap with reads of bi) ----
    if (t < 126) { stageA(bi2, t + 2); stageB(bi2, t + 2); }

    // ---- MFMA clusters; reads drain underneath via per-operand waits ----
    __builtin_amdgcn_s_setprio(1);
    #pragma unroll
    for (int mi = 0; mi < 4; ++mi)
      #pragma unroll
      for (int ni = 0; ni < 4; ++ni)
        acc[mi][ni] = __builtin_amdgcn_mfma_f32_16x16x32_f16(a0[mi], bf[ni], acc[mi][ni], 0, 0, 0);
    #pragma unroll
    for (int mi = 0; mi < 4; ++mi)
      #pragma unroll
      for (int ni = 0; ni < 4; ++ni)
        acc[4 + mi][ni] = __builtin_amdgcn_mfma_f32_16x16x32_f16(a1[mi], bf[ni], acc[4 + mi][ni], 0, 0, 0);
    __builtin_amdgcn_s_setprio(0);

    // ---- single tile-end sync: counted vmcnt then barrier ----
    if (t < 126) asm volatile("s_waitcnt vmcnt(4)" ::: "memory");
    else         asm volatile("s_waitcnt vmcnt(0)" ::: "memory");
    __builtin_amdgcn_s_barrier();

    // ---- per-panel epilogue: rowsum += tanh(acc + hproj) * v ----
    if ((t & 31) == 31) {
      const int nt = t >> 5;
      const int hb = (nt << 8) + (wc << 6);
      #pragma unroll
      for (int ni = 0; ni < 4; ++ni) {
        const int h = hb + (ni << 4) + l15;
        const float hv = hp_s[h];
        const float vv = vh_s[h];
        #pragma unroll
        for (int mi = 0; mi < 8; ++mi) {
          #pragma unroll
          for (int r = 0; r < 4; ++r)
            rowsum[mi][r] += fast_tanh(acc[mi][ni][r] + hv) * vv;
          acc[mi][ni] = (f32x4){0.f, 0.f, 0.f, 0.f};
        }
      }
    }
    bi = (bi >= 2) ? 0 : bi + 1;
  }

  // ---- reduce across the 16 column-lanes of each wave ----
  #pragma unroll
  for (int mi = 0; mi < 8; ++mi)
    #pragma unroll
    for (int r = 0; r < 4; ++r) {
      float s = rowsum[mi][r];
      s += __shfl_xor(s, 1);
      s += __shfl_xor(s, 2);
      s += __shfl_xor(s, 4);
      s += __shfl_xor(s, 8);
      rowsum[mi][r] = s;
    }
  __syncthreads();
  if (l15 == 0) {
    #pragma unroll
    for (int mi = 0; mi < 8; ++mi)
      #pragma unroll
      for (int r = 0; r < 4; ++r) {
        const int row = (wr << 7) + (mi << 4) + (qq << 2) + r;
        red[(row << 2) + wc] = rowsum[mi][r];
      }
  }
  __syncthreads();
  if (tid < 256) {
    const float s = red[tid << 2] + red[(tid << 2) + 1] + red[(tid << 2) + 2] + red[(tid << 2) + 3];
    const int m = m0 + tid;
    logits[m] = (mask[(b << 11) + (m & 2047)] == 0) ? NEGV : s;
  }
}

// ---------------------------------------------------------------------------
// softmax over S=2048 per batch row -> attention weights (output 1)
// ---------------------------------------------------------------------------
__global__ void softmax_kernel(const float* __restrict__ logits, float* __restrict__ wout) {
  __shared__ float red[4];
  const int b = blockIdx.x, tid = threadIdx.x;
  const int wid = tid >> 6, lane = tid & 63;
  const float* lb = logits + b * 2048;
  float x[8];
  #pragma unroll
  for (int j = 0; j < 8; ++j) x[j] = lb[tid + j * 256];
  float m = x[0];
  #pragma unroll
  for (int j = 1; j < 8; ++j) m = fmaxf(m, x[j]);
  #pragma unroll
  for (int off = 32; off > 0; off >>= 1) m = fmaxf(m, __shfl_xor(m, off));
  if (lane == 0) red[wid] = m;
  __syncthreads();
  m = fmaxf(fmaxf(red[0], red[1]), fmaxf(red[2], red[3]));
  __syncthreads();
  float e[8];
  float s = 0.f;
  #pragma unroll
  for (int j = 0; j < 8; ++j) { e[j] = expf(x[j] - m); s += e[j]; }
  #pragma unroll
  for (int off = 32; off > 0; off >>= 1) s += __shfl_xor(s, off);
  if (lane == 0) red[wid] = s;
  __syncthreads();
  s = red[0] + red[1] + red[2] + red[3];
  const float inv = 1.0f / s;
  #pragma unroll
  for (int j = 0; j < 8; ++j) wout[b * 2048 + tid + j * 256] = e[j] * inv;
}

// ---------------------------------------------------------------------------
// context from fp16 enc: ctx[b,e] = sum_s w[b,s] * enc16[b,s,e]
// ---------------------------------------------------------------------------
__global__ void context16_kernel(const _Float16* __restrict__ enc16,
                                 const float* __restrict__ wout, float* __restrict__ ctx) {
  const int b = blockIdx.x >> 4;
  const int ch = blockIdx.x & 15;
  const int tl = threadIdx.x & 127;  // e-granule: 8 cols
  const int sh = threadIdx.x >> 7;   // 0/1: s interleave
  float a[8] = {0.f, 0.f, 0.f, 0.f, 0.f, 0.f, 0.f, 0.f};
  #pragma unroll 1
  for (int i = 0; i < 64; ++i) {
    const int s = (ch << 7) + (i << 1) + sh;
    const float w = wout[(b << 11) + s];
    const half8 r = *(const half8*)(enc16 + (((size_t)(b << 11) + s) << 10) + (tl << 3));
    #pragma unroll
    for (int j = 0; j < 8; ++j) a[j] = fmaf(w, (float)r[j], a[j]);
  }
  float* c = ctx + (b << 10) + (tl << 3);
  #pragma unroll
  for (int j = 0; j < 8; ++j) atomicAdd(c + j, a[j]);
}

// ---------------------------------------------------------------------------
extern "C" void kernel_launch(void* const* d_in, const int* in_sizes, int n_in,
                              void* d_out, int out_size, void* d_ws, size_t ws_size,
                              hipStream_t stream) {
  const float* hidden = (const float*)d_in[0];
  const float* enc    = (const float*)d_in[1];
  const int*   mask   = (const int*)d_in[2];
  const float* W_h    = (const float*)d_in[3];
  const float* b_h    = (const float*)d_in[4];
  const float* W_e    = (const float*)d_in[5];
  const float* b_e    = (const float*)d_in[6];
  const float* v      = (const float*)d_in[7];

  float* ctx  = (float*)d_out;              // context: 32*1024 floats
  float* wout = (float*)d_out + 32 * 1024;  // attention weights: 32*2048 floats

  char* ws = (char*)d_ws;
  const size_t ENC16_BYTES = 134217728ULL;  // 32*2048*1024 fp16
  _Float16* enc16 = (_Float16*)ws;
  _Float16* W16T  = (_Float16*)(ws + ENC16_BYTES);
  float* hpb      = (float*)(ws + ENC16_BYTES + 2097152);
  float* logits   = (float*)(ws + ENC16_BYTES + 2097152 + 131072);

  hipMemsetAsync(ctx, 0, 32 * 1024 * sizeof(float), stream);
  hipLaunchKernelGGL(prep_kernel, dim3(1152 + 32768), dim3(256), 0, stream,
                     enc, enc16, W_e, W16T, hidden, W_h, b_h, b_e, hpb);
  hipLaunchKernelGGL(attn_gemm8_kernel, dim3(256), dim3(512), 0, stream,
                     enc16, W16T, hpb, v, mask, logits);
  hipLaunchKernelGGL(softmax_kernel, dim3(32), dim3(256), 0, stream, logits, wout);
  hipLaunchKernelGGL(context16_kernel, dim3(512), dim3(256), 0, stream, enc16, wout, ctx);
}